// Round 18
// baseline (53.072 us; speedup 1.0000x reference)
//
#include <hip/hip_runtime.h>
#include <hip/hip_fp16.h>

// DifferentiableRankIntegration, B=1024, tau=0.1, K=60.
// R18 = R17 with: NB=60 / W>=1.0 + 3-term tails (band 4.5 -> 3.3 u-units,
// x0.73 in-band work; rank-err budget is ~2.4, we're at ~0.2 -- headroom);
// load-balance permutation q=(tid*75)&255 for phase-4 quad ownership (modal
// quads spread across waves; removes the straggler-SIMD); coefficients
// interleaved (float4 + uint4 -> 2 ds_read_b128/quad); Tab/BktQ overlay the
// dead segCnt/segPre region -> pool 18880B, 8 blocks/CU.
// Algorithm: value-bucket compaction, en = e^{u-c_bkt} (cat in mantissa LSBs);
// in-band (ib-1..ib+1): exact weighted quartic rational (1 rcp / 4 a-terms,
// numerators via synthetic division, fp16-packed); out-of-band: 3-term sigma
// tails via geometric prefix/suffix tables (kappa^1..3 recurrences).

constexpr int B = 1024;
constexpr int NT = 256;
constexpr int NB = 60;
constexpr int SLOTCAP = 1216;      // 1024 + 3*NB pads, rounded to 16
constexpr int QCAP = SLOTCAP / 4;  // 304
constexpr float L2E = 1.4426950408889634f;
constexpr int TCOLS = NB + 6;      // 66

constexpr int OFF_EN  = 0;                        // 4864 B
constexpr int OFF_CQ  = OFF_EN + SLOTCAP * 4;     // CeAll+ChAll = 9728 B
                                                  //  (phase>=5: RankA/P 9728 B)
constexpr int OFF_SEG = OFF_CQ + 2 * QCAP * 16;   // segCnt uchar[60][16]=960,
                                                  //  segPre ushort[60][16]=1920
                                                  //  (phase>=3: Tab 14x66x4=3696)
constexpr int OFF_BKQ = OFF_SEG + 14 * TCOLS * 4; // BktQ 304 B
constexpr int OFF_SST = OFF_BKQ + QCAP;           // segStart 61*4 = 244 B
constexpr int OFF_RED = OFF_SST + (NB + 1) * 4;   // Red 32 B
constexpr int POOL_BYTES = ((OFF_RED + 32 + 15) / 16) * 16;  // 18880 B

__global__ __launch_bounds__(NT, 8)
void rank_one_kernel(const float* __restrict__ s_v, const float* __restrict__ s_l,
                     const int* __restrict__ pos_m, const int* __restrict__ neg_m,
                     float* __restrict__ rank_ws) {
    __shared__ __align__(16) char pool[POOL_BYTES];
    float* En          = (float*)(pool + OFF_EN);
    float4* CeAll      = (float4*)(pool + OFF_CQ);           // e1,e2,e3,e4
    uint4* ChAll       = (uint4*)(pool + OFF_CQ + QCAP*16);  // hA0,hA1,hP0,hP1
    unsigned char (*segCnt)[16]  = (unsigned char(*)[16])(pool + OFF_SEG);
    unsigned short (*segPre)[16] = (unsigned short(*)[16])(pool + OFF_SEG + NB*16);
    float* TabF        = (float*)(pool + OFF_SEG);   // overlay (post 2b)
    unsigned char* BktQ = (unsigned char*)(pool + OFF_BKQ);
    int* segStart      = (int*)(pool + OFF_SST);
    float* Red         = (float*)(pool + OFF_RED);
    float* RankA       = (float*)(pool + OFF_CQ);    // phase>=5 overlay
    float* RankP       = RankA + SLOTCAP;

    const int m = blockIdx.x >> 10;
    const int r = blockIdx.x & 1023;
    const float* __restrict__ S = m ? s_l : s_v;
    const int tid = threadIdx.x;
    const int lane = tid & 63;
    const int wvid = tid >> 6;
    const unsigned long long lmask = (1ull << lane) - 1ull;

    for (int s = tid; s < SLOTCAP; s += NT) En[s] = 0.f;  // pads: cat bits 0
    for (int j = tid; j < NB * 16 / 4; j += NT) ((int*)segCnt)[j] = 0;
    __syncthreads();

    // ---- Phase 1: read, u = s/tau, cat, row min/max ----
    float uu[4]; int cat[4];
    float mn = 1e30f, mx = -1e30f;
#pragma unroll
    for (int i = 0; i < 4; ++i) {
        const int c = tid + i * NT;
        uu[i] = S[r * B + c] * 10.0f;
        const int pf = pos_m[r * B + c] != 0, nf = neg_m[r * B + c] != 0;
        cat[i] = pf | (nf << 1);
        mn = fminf(mn, uu[i]); mx = fmaxf(mx, uu[i]);
    }
#pragma unroll
    for (int off = 1; off < 64; off <<= 1) {
        mn = fminf(mn, __shfl_xor(mn, off));
        mx = fmaxf(mx, __shfl_xor(mx, off));
    }
    if (lane == 0) { Red[wvid] = mn; Red[4 + wvid] = mx; }
    __syncthreads();

    const float lo = fminf(fminf(Red[0], Red[1]), fminf(Red[2], Red[3]));
    const float hi = fmaxf(fmaxf(Red[4], Red[5]), fmaxf(Red[6], Red[7]));
    const float umin = lo;
    const float Wb   = fmaxf((hi - lo) * (1.0001f / NB), 1.0f);
    const float invW = 1.0f / Wb;
    const float kap1 = exp2f(-Wb * L2E);
    const float kap2 = kap1 * kap1;
    const float kap3 = kap2 * kap1;
    const float eWm  = exp2f(Wb * L2E);

    // ---- Phase 1b: bucket keys; rank via 6 bit-ballots (NB<63, cat0 -> 63) ----
    int key[4], rk[4];
#pragma unroll
    for (int i = 0; i < 4; ++i) {
        int b = (int)((uu[i] - umin) * invW);
        b = b > NB - 1 ? NB - 1 : b;
        const int kk = cat[i] ? b : 63;
        key[i] = b;
        unsigned long long same = ~0ull;
#pragma unroll
        for (int j = 0; j < 6; ++j) {
            const unsigned long long bb = __ballot((kk >> j) & 1);
            same &= ((kk >> j) & 1) ? bb : ~bb;
        }
        rk[i] = (int)__popcll(same & lmask);
        if (cat[i] && rk[i] == 0)
            segCnt[kk][i * 4 + wvid] = (unsigned char)__popcll(same);
    }
    __syncthreads();

    // ---- Phase 2a: padded lengths + parallel unit-prefix table ----
    if (tid < NB) {
        int t = 0;
#pragma unroll
        for (int u = 0; u < 16; ++u) t += (int)segCnt[tid][u];
        segStart[tid] = (t + 3) & ~3;
    }
    for (int j = tid; j < NB * 16; j += NT) {
        const int k = j >> 4, u = j & 15;
        int p = 0;
        for (int v = 0; v < u; ++v) p += (int)segCnt[k][v];
        segPre[k][u] = (unsigned short)p;
    }
    __syncthreads();
    if (tid == 0) {
        int run = 0;
        for (int k = 0; k < NB; ++k) { int t = segStart[k]; segStart[k] = run; run += t; }
        segStart[NB] = run;
    }
    __syncthreads();

    // ---- Phase 2b: placement; slot in registers; cat in En mantissa LSBs ----
    int slot[4];
#pragma unroll
    for (int i = 0; i < 4; ++i) {
        slot[i] = 0;
        if (cat[i]) {
            const int k = key[i];
            slot[i] = segStart[k] + (int)segPre[k][i * 4 + wvid] + rk[i];
            const float cb = umin + ((float)k + 0.5f) * Wb;
            const float env = exp2f((uu[i] - cb) * L2E);
            unsigned eb = __float_as_uint(env);
            eb = (eb & ~3u) | (unsigned)cat[i];
            En[slot[i]] = __uint_as_float(eb);
        }
    }
    __syncthreads();     // segCnt/segPre dead -> Tab overlay valid

    const int nS = segStart[NB];
    const int nQ = nS >> 2;

    // ---- Phase 3a: Tab boundary zeros + quad coefficients + BktQ ----
    if (tid < 14 * 6) {                   // cols {0,1,62,63,64,65} per row
        const int row = tid / 6, ci = tid % 6;
        TabF[row * TCOLS + (ci < 2 ? ci : ci + 60)] = 0.f;  // disjoint from 3b's 2..61
    }
    for (int q = tid; q < nQ; q += NT) {
        int bq = 0;
        for (int k = 1; k < NB; ++k) bq += (4 * q >= segStart[k]);
        BktQ[q] = (unsigned char)bq;
        const float4 e4v = *(const float4*)&En[4 * q];
        const float en[4] = {e4v.x, e4v.y, e4v.z, e4v.w};
        const int fl[4] = {(int)(__float_as_uint(e4v.x) & 3u),
                           (int)(__float_as_uint(e4v.y) & 3u),
                           (int)(__float_as_uint(e4v.z) & 3u),
                           (int)(__float_as_uint(e4v.w) & 3u)};
        const float s01 = en[0] + en[1], p01 = en[0] * en[1];
        const float s23 = en[2] + en[3], p23 = en[2] * en[3];
        const float e1 = s01 + s23;
        const float e2 = fmaf(s01, s23, p01 + p23);
        const float e3 = fmaf(s01, p23, s23 * p01);
        const float e4 = p01 * p23;
        float nA3 = 0.f, nA2 = 0.f, nA1 = 0.f, nA0 = 0.f;
        float nP3 = 0.f, nP2 = 0.f, nP1 = 0.f, nP0 = 0.f;
#pragma unroll
        for (int j = 0; j < 4; ++j) {
            const float b1 = e1 - en[j];
            const float b2 = fmaf(-en[j], b1, e2);
            const float b3 = fmaf(-en[j], b2, e3);
            const float nn = (float)(fl[j] >> 1) * en[j];
            const float pp = (float)(fl[j] & 1) * en[j];
            nA3 += nn; nA2 = fmaf(nn, b1, nA2); nA1 = fmaf(nn, b2, nA1); nA0 = fmaf(nn, b3, nA0);
            nP3 += pp; nP2 = fmaf(pp, b1, nP2); nP1 = fmaf(pp, b2, nP1); nP0 = fmaf(pp, b3, nP0);
        }
        CeAll[q] = make_float4(e1, e2, e3, e4);
        __half2 hA0 = __floats2half2_rn(nA3, nA2);
        __half2 hA1 = __floats2half2_rn(nA1, nA0);
        __half2 hP0 = __floats2half2_rn(nP3, nP2);
        __half2 hP1 = __floats2half2_rn(nP1, nP0);
        ChAll[q] = make_uint4(reinterpret_cast<unsigned&>(hA0), reinterpret_cast<unsigned&>(hA1),
                              reinterpret_cast<unsigned&>(hP0), reinterpret_cast<unsigned&>(hP1));
    }
    // ---- Phase 3b: per-bucket tail sums, 4 threads/bucket + shfl reduce ----
    if (tid < NB * 4) {
        const int k = tid >> 2, o = tid & 3;
        float g1a=0,g2a=0,g3a=0,h1a=0,h2a=0,h3a=0,s0a=0;
        float g1p=0,g2p=0,g3p=0,h1p=0,h2p=0,h3p=0,s0p=0;
        for (int s = segStart[k] + o; s < segStart[k + 1]; s += 4) {
            const float en = En[s];
            const int f = (int)(__float_as_uint(en) & 3u);
            if (!f) continue;
            const float en2 = en * en, en3 = en2 * en;
            const float ren = __builtin_amdgcn_rcpf(en);
            const float ren2 = ren * ren, ren3 = ren2 * ren;
            const float nf = (float)(f >> 1), pf = (float)(f & 1);
            g1a = fmaf(nf,en,g1a);  g2a = fmaf(nf,en2,g2a);  g3a = fmaf(nf,en3,g3a);
            h1a = fmaf(nf,ren,h1a); h2a = fmaf(nf,ren2,h2a); h3a = fmaf(nf,ren3,h3a); s0a += nf;
            g1p = fmaf(pf,en,g1p);  g2p = fmaf(pf,en2,g2p);  g3p = fmaf(pf,en3,g3p);
            h1p = fmaf(pf,ren,h1p); h2p = fmaf(pf,ren2,h2p); h3p = fmaf(pf,ren3,h3p); s0p += pf;
        }
#define RED4(v) v += __shfl_xor(v, 2); v += __shfl_xor(v, 1)
        RED4(g1a); RED4(g2a); RED4(g3a); RED4(h1a); RED4(h2a); RED4(h3a); RED4(s0a);
        RED4(g1p); RED4(g2p); RED4(g3p); RED4(h1p); RED4(h2p); RED4(h3p); RED4(s0p);
#undef RED4
        if (o == 0) {
            TabF[(0*7+0)*TCOLS+k+2]=g1a; TabF[(0*7+1)*TCOLS+k+2]=g2a; TabF[(0*7+2)*TCOLS+k+2]=g3a;
            TabF[(0*7+3)*TCOLS+k+2]=h1a; TabF[(0*7+4)*TCOLS+k+2]=h2a; TabF[(0*7+5)*TCOLS+k+2]=h3a;
            TabF[(0*7+6)*TCOLS+k+2]=s0a;
            TabF[(1*7+0)*TCOLS+k+2]=g1p; TabF[(1*7+1)*TCOLS+k+2]=g2p; TabF[(1*7+2)*TCOLS+k+2]=g3p;
            TabF[(1*7+3)*TCOLS+k+2]=h1p; TabF[(1*7+4)*TCOLS+k+2]=h2p; TabF[(1*7+5)*TCOLS+k+2]=h3p;
            TabF[(1*7+6)*TCOLS+k+2]=s0p;
        }
    }
    __syncthreads();
    // ---- Phase 3c: geometric prefix/suffix scans, 14-way parallel ----
    if (tid < 14) {
        const int row = tid % 7;
        float* Trow = &TabF[tid * TCOLS];
        if (row < 3) {
            const float kp = row == 0 ? kap1 : (row == 1 ? kap2 : kap3);
            float r1 = 0.f;
            for (int k = 0; k < NB; ++k) { r1 = fmaf(r1, kp, Trow[k+2]); Trow[k+2] = r1; }
        } else if (row < 6) {
            const float kp = row == 3 ? kap1 : (row == 4 ? kap2 : kap3);
            float q1 = 0.f;
            for (int k = NB - 1; k >= 0; --k) { q1 = fmaf(q1, kp, Trow[k+2]); Trow[k+2] = q1; }
        } else {
            float s0 = 0.f;
            for (int k = NB - 1; k >= 0; --k) { s0 += Trow[k+2]; Trow[k+2] = s0; }
        }
    }
    __syncthreads();

    // ---- Phase 4: main — permuted quad ownership (load balance) ----
    float AN[4] = {0,0,0,0}, AP[4] = {0,0,0,0};
    const int q0 = (tid * 75) & 255;   // bijective on 0..255; spreads modal quads
    if (q0 < nQ) {
        const float4 x4 = *(const float4*)&En[4 * q0];
        const float xb[4] = {x4.x, x4.y, x4.z, x4.w};
        const int ib = BktQ[q0];
        const int klo = ib > 0 ? ib - 1 : 0;
        const int khi = ib < NB - 1 ? ib + 1 : NB - 1;
        const int qs  = segStart[klo] >> 2;
        const int qe  = segStart[khi + 1] >> 2;
        const int qo0 = segStart[ib] >> 2;
        const int qo1 = segStart[ib + 1] >> 2;

        auto quadrun = [&](int a0, int a1, const float* xs) {
            for (int q = a0; q < a1; ++q) {
                const float4 ce = CeAll[q];
                const uint4 ch = ChAll[q];
                const float2 a01 = __half22float2(*(const __half2*)&ch.x);
                const float2 a23 = __half22float2(*(const __half2*)&ch.y);
                const float2 p01 = __half22float2(*(const __half2*)&ch.z);
                const float2 p23 = __half22float2(*(const __half2*)&ch.w);
#pragma unroll
                for (int i = 0; i < 4; ++i) {
                    const float x = xs[i];
                    float t = x + ce.x; t = fmaf(t, x, ce.y); t = fmaf(t, x, ce.z);
                    const float D = fmaf(t, x, ce.w);
                    float u = fmaf(a01.x, x, a01.y); u = fmaf(u, x, a23.x);
                    const float NA = fmaf(u, x, a23.y);
                    float v = fmaf(p01.x, x, p01.y); v = fmaf(v, x, p23.x);
                    const float NP = fmaf(v, x, p23.y);
                    const float rd = __builtin_amdgcn_rcpf(D);
                    AN[i] = fmaf(NA, rd, AN[i]);
                    AP[i] = fmaf(NP, rd, AP[i]);
                }
            }
        };
        float xsl[4], xsh[4];
#pragma unroll
        for (int i = 0; i < 4; ++i) { xsl[i] = xb[i] * eWm; xsh[i] = xb[i] * kap1; }
        quadrun(qs,  qo0, xsl);   // below-band buckets: fc = e^W
        quadrun(qo0, qo1, xb);    // own bucket: fc = 1
        quadrun(qo1, qe,  xsh);   // above-band buckets: fc = kappa

        // 3-term out-of-band tails
        const float P1a = TabF[(0*7+0)*TCOLS+ib],   P2a = TabF[(0*7+1)*TCOLS+ib],   P3a = TabF[(0*7+2)*TCOLS+ib];
        const float S1a = TabF[(0*7+3)*TCOLS+ib+4], S2a = TabF[(0*7+4)*TCOLS+ib+4], S3a = TabF[(0*7+5)*TCOLS+ib+4];
        const float S0a = TabF[(0*7+6)*TCOLS+ib+4];
        const float P1p = TabF[(1*7+0)*TCOLS+ib],   P2p = TabF[(1*7+1)*TCOLS+ib],   P3p = TabF[(1*7+2)*TCOLS+ib];
        const float S1p = TabF[(1*7+3)*TCOLS+ib+4], S2p = TabF[(1*7+4)*TCOLS+ib+4], S3p = TabF[(1*7+5)*TCOLS+ib+4];
        const float S0p = TabF[(1*7+6)*TCOLS+ib+4];
#pragma unroll
        for (int i = 0; i < 4; ++i) {
            const float eb = xb[i];
            const float rb = __builtin_amdgcn_rcpf(eb);
            const float tq = rb * kap2, sq = eb * kap2;
            const float tq2 = tq * tq, tq3 = tq2 * tq;
            const float sq2 = sq * sq, sq3 = sq2 * sq;
            AN[i] += tq * P1a - tq2 * P2a + tq3 * P3a
                   + S0a - sq * S1a + sq2 * S2a - sq3 * S3a;
            AP[i] += tq * P1p - tq2 * P2p + tq3 * P3p
                   + S0p - sq * S1p + sq2 * S2p - sq3 * S3p;
        }
    }
    __syncthreads();   // all Cq reads done -> overlay RankA/RankP

    // ---- Phase 5: write ranks BY SLOT (per-quad, permuted) ----
    if (q0 < nQ) {
#pragma unroll
        for (int i = 0; i < 4; ++i) {
            RankA[4 * q0 + i] = AN[i];
            RankP[4 * q0 + i] = AP[i];
        }
    }
    __syncthreads();

    // ---- Phase 6: gather via register slot[], write rank_m ----
#pragma unroll
    for (int i = 0; i < 4; ++i) {
        const int c = tid + i * NT;
        const bool pf = (cat[i] & 1) != 0;
        const bool nf = (cat[i] & 2) != 0;
        const float rk_ = (pf ? 1.f + RankA[slot[i]] : 0.f) +
                          (nf ? 1.f + RankP[slot[i]] : 0.f);
        rank_ws[m * (B * B) + r * B + c] = rk_;
    }
}

__global__ __launch_bounds__(NT, 8)
void combine_kernel(const float* __restrict__ rank_ws,
                    const float* __restrict__ w_v, const float* __restrict__ w_l,
                    float* __restrict__ out) {
    const int i4 = (blockIdx.x * NT + threadIdx.x) * 4;
    const float4 rv = *(const float4*)&rank_ws[i4];
    const float4 rl = *(const float4*)&rank_ws[B * B + i4];
    const float4 wv = *(const float4*)&w_v[i4];
    const float4 wl = *(const float4*)&w_l[i4];
    float4 o;
    o.x = 61.f * (wv.x / (60.f + rv.x) + wl.x / (60.f + rl.x));
    o.y = 61.f * (wv.y / (60.f + rv.y) + wl.y / (60.f + rl.y));
    o.z = 61.f * (wv.z / (60.f + rv.z) + wl.z / (60.f + rl.z));
    o.w = 61.f * (wv.w / (60.f + rv.w) + wl.w / (60.f + rl.w));
    *(float4*)&out[i4] = o;
}

extern "C" void kernel_launch(void* const* d_in, const int* in_sizes, int n_in,
                              void* d_out, int out_size, void* d_ws, size_t ws_size,
                              hipStream_t stream) {
    const float* s_v = (const float*)d_in[0];
    const float* s_l = (const float*)d_in[1];
    const int* pos_mask = (const int*)d_in[2];
    const int* neg_mask = (const int*)d_in[3];
    const float* w_v = (const float*)d_in[4];
    const float* w_l = (const float*)d_in[5];
    float* out = (float*)d_out;
    float* rank_ws = (float*)d_ws;   // 2 * 1024 * 1024 floats = 8 MB

    rank_one_kernel<<<2 * B, NT, 0, stream>>>(s_v, s_l, pos_mask, neg_mask, rank_ws);
    combine_kernel<<<(B * B) / (NT * 4), NT, 0, stream>>>(rank_ws, w_v, w_l, out);
}

// Round 19
// 51.808 us; speedup vs baseline: 1.0244x; 1.0244x over previous
//
#include <hip/hip_runtime.h>
#include <hip/hip_fp16.h>

// DifferentiableRankIntegration, B=1024, tau=0.1, K=60.
// R19 = R18 with the load-balance permutation moved to 16-thread-group
// granularity (wave samples 4 spread quad-groups -> balanced; quads within a
// group contiguous -> shared ib -> broadcast LDS reads preserved) and a
// bank-skewed coefficient layout p(q)=q+(q>>4) (+16B per 16-quad group) so
// the 4 groups of a wave read disjoint bank sets. Numerics identical to R18.
// Algorithm: value-bucket compaction (NB=60, W>=1.0), en = e^{u-c_bkt} (cat
// in mantissa LSBs); in-band (ib-1..ib+1): exact weighted quartic rational
// (1 rcp / 4 a-terms, numerators via synthetic division, fp16-packed);
// out-of-band: 3-term sigma tails via geometric prefix/suffix tables.

constexpr int B = 1024;
constexpr int NT = 256;
constexpr int NB = 60;
constexpr int SLOTCAP = 1216;      // 1024 + 3*NB pads, rounded to 16
constexpr int QCAP = SLOTCAP / 4;  // 304
constexpr int QPHYS = QCAP + (QCAP >> 4) + 1;  // 324 (skewed physical slots)
constexpr float L2E = 1.4426950408889634f;
constexpr int TCOLS = NB + 6;      // 66

constexpr int OFF_EN  = 0;                        // 4864 B
constexpr int OFF_CQ  = OFF_EN + SLOTCAP * 4;     // CeAll+ChAll = 2*324*16 = 10368 B
                                                  //  (phase>=5: RankA/P 9728 B)
constexpr int OFF_SEG = OFF_CQ + 2 * QPHYS * 16;  // segCnt 960 + segPre 1920
                                                  //  (phase>=3: Tab 14x66x4 = 3696)
constexpr int OFF_BKQ = OFF_SEG + 14 * TCOLS * 4; // BktQ 304 B
constexpr int OFF_SST = OFF_BKQ + QCAP;           // segStart 61*4 = 244 B
constexpr int OFF_RED = OFF_SST + (NB + 1) * 4;   // Red 32 B
constexpr int POOL_BYTES = ((OFF_RED + 32 + 15) / 16) * 16;  // 19520 B <= 20480

__global__ __launch_bounds__(NT, 8)
void rank_one_kernel(const float* __restrict__ s_v, const float* __restrict__ s_l,
                     const int* __restrict__ pos_m, const int* __restrict__ neg_m,
                     float* __restrict__ rank_ws) {
    __shared__ __align__(16) char pool[POOL_BYTES];
    float* En          = (float*)(pool + OFF_EN);
    float4* CeAll      = (float4*)(pool + OFF_CQ);            // e1..e4 (skewed)
    uint4* ChAll       = (uint4*)(pool + OFF_CQ + QPHYS*16);  // hA0,hA1,hP0,hP1
    unsigned char (*segCnt)[16]  = (unsigned char(*)[16])(pool + OFF_SEG);
    unsigned short (*segPre)[16] = (unsigned short(*)[16])(pool + OFF_SEG + NB*16);
    float* TabF        = (float*)(pool + OFF_SEG);   // overlay (post 2b)
    unsigned char* BktQ = (unsigned char*)(pool + OFF_BKQ);
    int* segStart      = (int*)(pool + OFF_SST);
    float* Red         = (float*)(pool + OFF_RED);
    float* RankA       = (float*)(pool + OFF_CQ);    // phase>=5 overlay
    float* RankP       = RankA + SLOTCAP;

    const int m = blockIdx.x >> 10;
    const int r = blockIdx.x & 1023;
    const float* __restrict__ S = m ? s_l : s_v;
    const int tid = threadIdx.x;
    const int lane = tid & 63;
    const int wvid = tid >> 6;
    const unsigned long long lmask = (1ull << lane) - 1ull;

    for (int s = tid; s < SLOTCAP; s += NT) En[s] = 0.f;  // pads: cat bits 0
    for (int j = tid; j < NB * 16 / 4; j += NT) ((int*)segCnt)[j] = 0;
    __syncthreads();

    // ---- Phase 1: read, u = s/tau, cat, row min/max ----
    float uu[4]; int cat[4];
    float mn = 1e30f, mx = -1e30f;
#pragma unroll
    for (int i = 0; i < 4; ++i) {
        const int c = tid + i * NT;
        uu[i] = S[r * B + c] * 10.0f;
        const int pf = pos_m[r * B + c] != 0, nf = neg_m[r * B + c] != 0;
        cat[i] = pf | (nf << 1);
        mn = fminf(mn, uu[i]); mx = fmaxf(mx, uu[i]);
    }
#pragma unroll
    for (int off = 1; off < 64; off <<= 1) {
        mn = fminf(mn, __shfl_xor(mn, off));
        mx = fmaxf(mx, __shfl_xor(mx, off));
    }
    if (lane == 0) { Red[wvid] = mn; Red[4 + wvid] = mx; }
    __syncthreads();

    const float lo = fminf(fminf(Red[0], Red[1]), fminf(Red[2], Red[3]));
    const float hi = fmaxf(fmaxf(Red[4], Red[5]), fmaxf(Red[6], Red[7]));
    const float umin = lo;
    const float Wb   = fmaxf((hi - lo) * (1.0001f / NB), 1.0f);
    const float invW = 1.0f / Wb;
    const float kap1 = exp2f(-Wb * L2E);
    const float kap2 = kap1 * kap1;
    const float kap3 = kap2 * kap1;
    const float eWm  = exp2f(Wb * L2E);

    // ---- Phase 1b: bucket keys; rank via 6 bit-ballots (NB<63, cat0 -> 63) ----
    int key[4], rk[4];
#pragma unroll
    for (int i = 0; i < 4; ++i) {
        int b = (int)((uu[i] - umin) * invW);
        b = b > NB - 1 ? NB - 1 : b;
        const int kk = cat[i] ? b : 63;
        key[i] = b;
        unsigned long long same = ~0ull;
#pragma unroll
        for (int j = 0; j < 6; ++j) {
            const unsigned long long bb = __ballot((kk >> j) & 1);
            same &= ((kk >> j) & 1) ? bb : ~bb;
        }
        rk[i] = (int)__popcll(same & lmask);
        if (cat[i] && rk[i] == 0)
            segCnt[kk][i * 4 + wvid] = (unsigned char)__popcll(same);
    }
    __syncthreads();

    // ---- Phase 2a: padded lengths + parallel unit-prefix table ----
    if (tid < NB) {
        int t = 0;
#pragma unroll
        for (int u = 0; u < 16; ++u) t += (int)segCnt[tid][u];
        segStart[tid] = (t + 3) & ~3;
    }
    for (int j = tid; j < NB * 16; j += NT) {
        const int k = j >> 4, u = j & 15;
        int p = 0;
        for (int v = 0; v < u; ++v) p += (int)segCnt[k][v];
        segPre[k][u] = (unsigned short)p;
    }
    __syncthreads();
    if (tid == 0) {
        int run = 0;
        for (int k = 0; k < NB; ++k) { int t = segStart[k]; segStart[k] = run; run += t; }
        segStart[NB] = run;
    }
    __syncthreads();

    // ---- Phase 2b: placement; slot in registers; cat in En mantissa LSBs ----
    int slot[4];
#pragma unroll
    for (int i = 0; i < 4; ++i) {
        slot[i] = 0;
        if (cat[i]) {
            const int k = key[i];
            slot[i] = segStart[k] + (int)segPre[k][i * 4 + wvid] + rk[i];
            const float cb = umin + ((float)k + 0.5f) * Wb;
            const float env = exp2f((uu[i] - cb) * L2E);
            unsigned eb = __float_as_uint(env);
            eb = (eb & ~3u) | (unsigned)cat[i];
            En[slot[i]] = __uint_as_float(eb);
        }
    }
    __syncthreads();     // segCnt/segPre dead -> Tab overlay valid

    const int nS = segStart[NB];
    const int nQ = nS >> 2;

    // ---- Phase 3a: Tab boundary zeros + quad coefficients (skewed) + BktQ ----
    if (tid < 14 * 6) {                   // cols {0,1,62,63,64,65} per row
        const int row = tid / 6, ci = tid % 6;
        TabF[row * TCOLS + (ci < 2 ? ci : ci + 60)] = 0.f;  // disjoint from 3b's 2..61
    }
    for (int q = tid; q < nQ; q += NT) {
        int bq = 0;
        for (int k = 1; k < NB; ++k) bq += (4 * q >= segStart[k]);
        BktQ[q] = (unsigned char)bq;
        const float4 e4v = *(const float4*)&En[4 * q];
        const float en[4] = {e4v.x, e4v.y, e4v.z, e4v.w};
        const int fl[4] = {(int)(__float_as_uint(e4v.x) & 3u),
                           (int)(__float_as_uint(e4v.y) & 3u),
                           (int)(__float_as_uint(e4v.z) & 3u),
                           (int)(__float_as_uint(e4v.w) & 3u)};
        const float s01 = en[0] + en[1], p01 = en[0] * en[1];
        const float s23 = en[2] + en[3], p23 = en[2] * en[3];
        const float e1 = s01 + s23;
        const float e2 = fmaf(s01, s23, p01 + p23);
        const float e3 = fmaf(s01, p23, s23 * p01);
        const float e4 = p01 * p23;
        float nA3 = 0.f, nA2 = 0.f, nA1 = 0.f, nA0 = 0.f;
        float nP3 = 0.f, nP2 = 0.f, nP1 = 0.f, nP0 = 0.f;
#pragma unroll
        for (int j = 0; j < 4; ++j) {
            const float b1 = e1 - en[j];
            const float b2 = fmaf(-en[j], b1, e2);
            const float b3 = fmaf(-en[j], b2, e3);
            const float nn = (float)(fl[j] >> 1) * en[j];
            const float pp = (float)(fl[j] & 1) * en[j];
            nA3 += nn; nA2 = fmaf(nn, b1, nA2); nA1 = fmaf(nn, b2, nA1); nA0 = fmaf(nn, b3, nA0);
            nP3 += pp; nP2 = fmaf(pp, b1, nP2); nP1 = fmaf(pp, b2, nP1); nP0 = fmaf(pp, b3, nP0);
        }
        const int pq = q + (q >> 4);   // bank-skewed physical index
        CeAll[pq] = make_float4(e1, e2, e3, e4);
        __half2 hA0 = __floats2half2_rn(nA3, nA2);
        __half2 hA1 = __floats2half2_rn(nA1, nA0);
        __half2 hP0 = __floats2half2_rn(nP3, nP2);
        __half2 hP1 = __floats2half2_rn(nP1, nP0);
        ChAll[pq] = make_uint4(reinterpret_cast<unsigned&>(hA0), reinterpret_cast<unsigned&>(hA1),
                               reinterpret_cast<unsigned&>(hP0), reinterpret_cast<unsigned&>(hP1));
    }
    // ---- Phase 3b: per-bucket tail sums, 4 threads/bucket + shfl reduce ----
    if (tid < NB * 4) {
        const int k = tid >> 2, o = tid & 3;
        float g1a=0,g2a=0,g3a=0,h1a=0,h2a=0,h3a=0,s0a=0;
        float g1p=0,g2p=0,g3p=0,h1p=0,h2p=0,h3p=0,s0p=0;
        for (int s = segStart[k] + o; s < segStart[k + 1]; s += 4) {
            const float en = En[s];
            const int f = (int)(__float_as_uint(en) & 3u);
            if (!f) continue;
            const float en2 = en * en, en3 = en2 * en;
            const float ren = __builtin_amdgcn_rcpf(en);
            const float ren2 = ren * ren, ren3 = ren2 * ren;
            const float nf = (float)(f >> 1), pf = (float)(f & 1);
            g1a = fmaf(nf,en,g1a);  g2a = fmaf(nf,en2,g2a);  g3a = fmaf(nf,en3,g3a);
            h1a = fmaf(nf,ren,h1a); h2a = fmaf(nf,ren2,h2a); h3a = fmaf(nf,ren3,h3a); s0a += nf;
            g1p = fmaf(pf,en,g1p);  g2p = fmaf(pf,en2,g2p);  g3p = fmaf(pf,en3,g3p);
            h1p = fmaf(pf,ren,h1p); h2p = fmaf(pf,ren2,h2p); h3p = fmaf(pf,ren3,h3p); s0p += pf;
        }
#define RED4(v) v += __shfl_xor(v, 2); v += __shfl_xor(v, 1)
        RED4(g1a); RED4(g2a); RED4(g3a); RED4(h1a); RED4(h2a); RED4(h3a); RED4(s0a);
        RED4(g1p); RED4(g2p); RED4(g3p); RED4(h1p); RED4(h2p); RED4(h3p); RED4(s0p);
#undef RED4
        if (o == 0) {
            TabF[(0*7+0)*TCOLS+k+2]=g1a; TabF[(0*7+1)*TCOLS+k+2]=g2a; TabF[(0*7+2)*TCOLS+k+2]=g3a;
            TabF[(0*7+3)*TCOLS+k+2]=h1a; TabF[(0*7+4)*TCOLS+k+2]=h2a; TabF[(0*7+5)*TCOLS+k+2]=h3a;
            TabF[(0*7+6)*TCOLS+k+2]=s0a;
            TabF[(1*7+0)*TCOLS+k+2]=g1p; TabF[(1*7+1)*TCOLS+k+2]=g2p; TabF[(1*7+2)*TCOLS+k+2]=g3p;
            TabF[(1*7+3)*TCOLS+k+2]=h1p; TabF[(1*7+4)*TCOLS+k+2]=h2p; TabF[(1*7+5)*TCOLS+k+2]=h3p;
            TabF[(1*7+6)*TCOLS+k+2]=s0p;
        }
    }
    __syncthreads();
    // ---- Phase 3c: geometric prefix/suffix scans, 14-way parallel ----
    if (tid < 14) {
        const int row = tid % 7;
        float* Trow = &TabF[tid * TCOLS];
        if (row < 3) {
            const float kp = row == 0 ? kap1 : (row == 1 ? kap2 : kap3);
            float r1 = 0.f;
            for (int k = 0; k < NB; ++k) { r1 = fmaf(r1, kp, Trow[k+2]); Trow[k+2] = r1; }
        } else if (row < 6) {
            const float kp = row == 3 ? kap1 : (row == 4 ? kap2 : kap3);
            float q1 = 0.f;
            for (int k = NB - 1; k >= 0; --k) { q1 = fmaf(q1, kp, Trow[k+2]); Trow[k+2] = q1; }
        } else {
            float s0 = 0.f;
            for (int k = NB - 1; k >= 0; --k) { s0 += Trow[k+2]; Trow[k+2] = s0; }
        }
    }
    __syncthreads();

    // ---- Phase 4: main — group-permuted quad ownership (balance + broadcast) ----
    float AN[4] = {0,0,0,0}, AP[4] = {0,0,0,0};
    const int qg = ((tid >> 4) * 5) & 15;        // bijective on 16 groups
    const int q0 = qg * 16 + (tid & 15);         // contiguous within group
    if (q0 < nQ) {
        const float4 x4 = *(const float4*)&En[4 * q0];
        const float xb[4] = {x4.x, x4.y, x4.z, x4.w};
        const int ib = BktQ[q0];
        const int klo = ib > 0 ? ib - 1 : 0;
        const int khi = ib < NB - 1 ? ib + 1 : NB - 1;
        const int qs  = segStart[klo] >> 2;
        const int qe  = segStart[khi + 1] >> 2;
        const int qo0 = segStart[ib] >> 2;
        const int qo1 = segStart[ib + 1] >> 2;

        auto quadrun = [&](int a0, int a1, const float* xs) {
            for (int q = a0; q < a1; ++q) {
                const int pq = q + (q >> 4);
                const float4 ce = CeAll[pq];
                const uint4 ch = ChAll[pq];
                const float2 a01 = __half22float2(*(const __half2*)&ch.x);
                const float2 a23 = __half22float2(*(const __half2*)&ch.y);
                const float2 p01 = __half22float2(*(const __half2*)&ch.z);
                const float2 p23 = __half22float2(*(const __half2*)&ch.w);
#pragma unroll
                for (int i = 0; i < 4; ++i) {
                    const float x = xs[i];
                    float t = x + ce.x; t = fmaf(t, x, ce.y); t = fmaf(t, x, ce.z);
                    const float D = fmaf(t, x, ce.w);
                    float u = fmaf(a01.x, x, a01.y); u = fmaf(u, x, a23.x);
                    const float NA = fmaf(u, x, a23.y);
                    float v = fmaf(p01.x, x, p01.y); v = fmaf(v, x, p23.x);
                    const float NP = fmaf(v, x, p23.y);
                    const float rd = __builtin_amdgcn_rcpf(D);
                    AN[i] = fmaf(NA, rd, AN[i]);
                    AP[i] = fmaf(NP, rd, AP[i]);
                }
            }
        };
        float xsl[4], xsh[4];
#pragma unroll
        for (int i = 0; i < 4; ++i) { xsl[i] = xb[i] * eWm; xsh[i] = xb[i] * kap1; }
        quadrun(qs,  qo0, xsl);   // below-band buckets: fc = e^W
        quadrun(qo0, qo1, xb);    // own bucket: fc = 1
        quadrun(qo1, qe,  xsh);   // above-band buckets: fc = kappa

        // 3-term out-of-band tails
        const float P1a = TabF[(0*7+0)*TCOLS+ib],   P2a = TabF[(0*7+1)*TCOLS+ib],   P3a = TabF[(0*7+2)*TCOLS+ib];
        const float S1a = TabF[(0*7+3)*TCOLS+ib+4], S2a = TabF[(0*7+4)*TCOLS+ib+4], S3a = TabF[(0*7+5)*TCOLS+ib+4];
        const float S0a = TabF[(0*7+6)*TCOLS+ib+4];
        const float P1p = TabF[(1*7+0)*TCOLS+ib],   P2p = TabF[(1*7+1)*TCOLS+ib],   P3p = TabF[(1*7+2)*TCOLS+ib];
        const float S1p = TabF[(1*7+3)*TCOLS+ib+4], S2p = TabF[(1*7+4)*TCOLS+ib+4], S3p = TabF[(1*7+5)*TCOLS+ib+4];
        const float S0p = TabF[(1*7+6)*TCOLS+ib+4];
#pragma unroll
        for (int i = 0; i < 4; ++i) {
            const float eb = xb[i];
            const float rb = __builtin_amdgcn_rcpf(eb);
            const float tq = rb * kap2, sq = eb * kap2;
            const float tq2 = tq * tq, tq3 = tq2 * tq;
            const float sq2 = sq * sq, sq3 = sq2 * sq;
            AN[i] += tq * P1a - tq2 * P2a + tq3 * P3a
                   + S0a - sq * S1a + sq2 * S2a - sq3 * S3a;
            AP[i] += tq * P1p - tq2 * P2p + tq3 * P3p
                   + S0p - sq * S1p + sq2 * S2p - sq3 * S3p;
        }
    }
    __syncthreads();   // all Cq reads done -> overlay RankA/RankP

    // ---- Phase 5: write ranks BY SLOT (per-quad, group-permuted) ----
    if (q0 < nQ) {
#pragma unroll
        for (int i = 0; i < 4; ++i) {
            RankA[4 * q0 + i] = AN[i];
            RankP[4 * q0 + i] = AP[i];
        }
    }
    __syncthreads();

    // ---- Phase 6: gather via register slot[], write rank_m ----
#pragma unroll
    for (int i = 0; i < 4; ++i) {
        const int c = tid + i * NT;
        const bool pf = (cat[i] & 1) != 0;
        const bool nf = (cat[i] & 2) != 0;
        const float rk_ = (pf ? 1.f + RankA[slot[i]] : 0.f) +
                          (nf ? 1.f + RankP[slot[i]] : 0.f);
        rank_ws[m * (B * B) + r * B + c] = rk_;
    }
}

__global__ __launch_bounds__(NT, 8)
void combine_kernel(const float* __restrict__ rank_ws,
                    const float* __restrict__ w_v, const float* __restrict__ w_l,
                    float* __restrict__ out) {
    const int i4 = (blockIdx.x * NT + threadIdx.x) * 4;
    const float4 rv = *(const float4*)&rank_ws[i4];
    const float4 rl = *(const float4*)&rank_ws[B * B + i4];
    const float4 wv = *(const float4*)&w_v[i4];
    const float4 wl = *(const float4*)&w_l[i4];
    float4 o;
    o.x = 61.f * (wv.x / (60.f + rv.x) + wl.x / (60.f + rl.x));
    o.y = 61.f * (wv.y / (60.f + rv.y) + wl.y / (60.f + rl.y));
    o.z = 61.f * (wv.z / (60.f + rv.z) + wl.z / (60.f + rl.z));
    o.w = 61.f * (wv.w / (60.f + rv.w) + wl.w / (60.f + rl.w));
    *(float4*)&out[i4] = o;
}

extern "C" void kernel_launch(void* const* d_in, const int* in_sizes, int n_in,
                              void* d_out, int out_size, void* d_ws, size_t ws_size,
                              hipStream_t stream) {
    const float* s_v = (const float*)d_in[0];
    const float* s_l = (const float*)d_in[1];
    const int* pos_mask = (const int*)d_in[2];
    const int* neg_mask = (const int*)d_in[3];
    const float* w_v = (const float*)d_in[4];
    const float* w_l = (const float*)d_in[5];
    float* out = (float*)d_out;
    float* rank_ws = (float*)d_ws;   // 2 * 1024 * 1024 floats = 8 MB

    rank_one_kernel<<<2 * B, NT, 0, stream>>>(s_v, s_l, pos_mask, neg_mask, rank_ws);
    combine_kernel<<<(B * B) / (NT * 4), NT, 0, stream>>>(rank_ws, w_v, w_l, out);
}

// Round 20
// 48.652 us; speedup vs baseline: 1.0909x; 1.0649x over previous
//
#include <hip/hip_runtime.h>
#include <hip/hip_fp16.h>

// DifferentiableRankIntegration, B=1024, tau=0.1, K=60.
// R20 = R19 with: (1) phase-4 permutation removed (divergent loop bounds make
// wave cost = max over lanes; contiguous ownership is within-wave homogeneous),
// (2) serial 60-iter LDS scans replaced by wave-parallel shfl scans (2a bucket
// prefix: Hillis-Steele on wave 0; 3c geometric recurrences: multiplier-squared
// shfl scans, 14 rows over 4 waves) -- removes ~5.4K dependent cycles/block,
// (3) NB=60 / W>=1.0 + 3-term tails + bank-skewed coeffs retained.
// Algorithm: value-bucket compaction, en = e^{u-c_bkt} (cat in mantissa LSBs);
// in-band (ib-1..ib+1): exact weighted quartic rational (1 rcp / 4 a-terms,
// numerators via synthetic division, fp16-packed); out-of-band: 3-term sigma
// tails via geometric prefix/suffix tables.

constexpr int B = 1024;
constexpr int NT = 256;
constexpr int NB = 60;
constexpr int SLOTCAP = 1216;      // 1024 + 3*NB pads, rounded to 16
constexpr int QCAP = SLOTCAP / 4;  // 304
constexpr int QPHYS = QCAP + (QCAP >> 4) + 1;  // 324 (skewed physical slots)
constexpr float L2E = 1.4426950408889634f;
constexpr int TCOLS = NB + 6;      // 66

constexpr int OFF_EN  = 0;                        // 4864 B
constexpr int OFF_CQ  = OFF_EN + SLOTCAP * 4;     // CeAll+ChAll = 2*324*16 = 10368 B
                                                  //  (phase>=5: RankA/P 9728 B)
constexpr int OFF_SEG = OFF_CQ + 2 * QPHYS * 16;  // segCnt 960 + segPre 1920
                                                  //  (phase>=3: Tab 14x66x4 = 3696)
constexpr int OFF_BKQ = OFF_SEG + 14 * TCOLS * 4; // BktQ 304 B
constexpr int OFF_SST = OFF_BKQ + QCAP;           // segStart 61*4 = 244 B
constexpr int OFF_RED = OFF_SST + (NB + 1) * 4;   // Red 32 B
constexpr int POOL_BYTES = ((OFF_RED + 32 + 15) / 16) * 16;  // 19520 B <= 20480

__global__ __launch_bounds__(NT, 8)
void rank_one_kernel(const float* __restrict__ s_v, const float* __restrict__ s_l,
                     const int* __restrict__ pos_m, const int* __restrict__ neg_m,
                     float* __restrict__ rank_ws) {
    __shared__ __align__(16) char pool[POOL_BYTES];
    float* En          = (float*)(pool + OFF_EN);
    float4* CeAll      = (float4*)(pool + OFF_CQ);            // e1..e4 (skewed)
    uint4* ChAll       = (uint4*)(pool + OFF_CQ + QPHYS*16);  // hA0,hA1,hP0,hP1
    unsigned char (*segCnt)[16]  = (unsigned char(*)[16])(pool + OFF_SEG);
    unsigned short (*segPre)[16] = (unsigned short(*)[16])(pool + OFF_SEG + NB*16);
    float* TabF        = (float*)(pool + OFF_SEG);   // overlay (post 2b)
    unsigned char* BktQ = (unsigned char*)(pool + OFF_BKQ);
    int* segStart      = (int*)(pool + OFF_SST);
    float* Red         = (float*)(pool + OFF_RED);
    float* RankA       = (float*)(pool + OFF_CQ);    // phase>=5 overlay
    float* RankP       = RankA + SLOTCAP;

    const int m = blockIdx.x >> 10;
    const int r = blockIdx.x & 1023;
    const float* __restrict__ S = m ? s_l : s_v;
    const int tid = threadIdx.x;
    const int lane = tid & 63;
    const int wvid = tid >> 6;
    const unsigned long long lmask = (1ull << lane) - 1ull;

    for (int s = tid; s < SLOTCAP; s += NT) En[s] = 0.f;  // pads: cat bits 0
    for (int j = tid; j < NB * 16 / 4; j += NT) ((int*)segCnt)[j] = 0;
    __syncthreads();

    // ---- Phase 1: read, u = s/tau, cat, row min/max ----
    float uu[4]; int cat[4];
    float mn = 1e30f, mx = -1e30f;
#pragma unroll
    for (int i = 0; i < 4; ++i) {
        const int c = tid + i * NT;
        uu[i] = S[r * B + c] * 10.0f;
        const int pf = pos_m[r * B + c] != 0, nf = neg_m[r * B + c] != 0;
        cat[i] = pf | (nf << 1);
        mn = fminf(mn, uu[i]); mx = fmaxf(mx, uu[i]);
    }
#pragma unroll
    for (int off = 1; off < 64; off <<= 1) {
        mn = fminf(mn, __shfl_xor(mn, off));
        mx = fmaxf(mx, __shfl_xor(mx, off));
    }
    if (lane == 0) { Red[wvid] = mn; Red[4 + wvid] = mx; }
    __syncthreads();

    const float lo = fminf(fminf(Red[0], Red[1]), fminf(Red[2], Red[3]));
    const float hi = fmaxf(fmaxf(Red[4], Red[5]), fmaxf(Red[6], Red[7]));
    const float umin = lo;
    const float Wb   = fmaxf((hi - lo) * (1.0001f / NB), 1.0f);
    const float invW = 1.0f / Wb;
    const float kap1 = exp2f(-Wb * L2E);
    const float kap2 = kap1 * kap1;
    const float kap3 = kap2 * kap1;
    const float eWm  = exp2f(Wb * L2E);

    // ---- Phase 1b: bucket keys; rank via 6 bit-ballots (NB<63, cat0 -> 63) ----
    int key[4], rk[4];
#pragma unroll
    for (int i = 0; i < 4; ++i) {
        int b = (int)((uu[i] - umin) * invW);
        b = b > NB - 1 ? NB - 1 : b;
        const int kk = cat[i] ? b : 63;
        key[i] = b;
        unsigned long long same = ~0ull;
#pragma unroll
        for (int j = 0; j < 6; ++j) {
            const unsigned long long bb = __ballot((kk >> j) & 1);
            same &= ((kk >> j) & 1) ? bb : ~bb;
        }
        rk[i] = (int)__popcll(same & lmask);
        if (cat[i] && rk[i] == 0)
            segCnt[kk][i * 4 + wvid] = (unsigned char)__popcll(same);
    }
    __syncthreads();

    // ---- Phase 2a: segPre (parallel) + wave-0 shfl prefix scan of lengths ----
    for (int j = tid; j < NB * 16; j += NT) {
        const int k = j >> 4, u = j & 15;
        int p = 0;
        for (int v = 0; v < u; ++v) p += (int)segCnt[k][v];
        segPre[k][u] = (unsigned short)p;
    }
    if (wvid == 0) {
        int t = 0;
        if (lane < NB) {
#pragma unroll
            for (int u = 0; u < 16; ++u) t += (int)segCnt[lane][u];
            t = (t + 3) & ~3;
        }
        int inc = t;
#pragma unroll
        for (int d = 1; d < 64; d <<= 1) {
            const int o = __shfl_up(inc, d);
            if (lane >= d) inc += o;
        }
        if (lane < NB) segStart[lane] = inc - t;
        if (lane == NB - 1) segStart[NB] = inc;
    }
    __syncthreads();

    // ---- Phase 2b: placement; slot in registers; cat in En mantissa LSBs ----
    int slot[4];
#pragma unroll
    for (int i = 0; i < 4; ++i) {
        slot[i] = 0;
        if (cat[i]) {
            const int k = key[i];
            slot[i] = segStart[k] + (int)segPre[k][i * 4 + wvid] + rk[i];
            const float cb = umin + ((float)k + 0.5f) * Wb;
            const float env = exp2f((uu[i] - cb) * L2E);
            unsigned eb = __float_as_uint(env);
            eb = (eb & ~3u) | (unsigned)cat[i];
            En[slot[i]] = __uint_as_float(eb);
        }
    }
    __syncthreads();     // segCnt/segPre dead -> Tab overlay valid

    const int nS = segStart[NB];
    const int nQ = nS >> 2;

    // ---- Phase 3a: Tab boundary zeros + quad coefficients (skewed) + BktQ ----
    if (tid < 14 * 6) {                   // cols {0,1,62,63,64,65} per row
        const int row = tid / 6, ci = tid % 6;
        TabF[row * TCOLS + (ci < 2 ? ci : ci + 60)] = 0.f;  // disjoint from 3b's 2..61
    }
    for (int q = tid; q < nQ; q += NT) {
        int bq = 0;
        for (int k = 1; k < NB; ++k) bq += (4 * q >= segStart[k]);
        BktQ[q] = (unsigned char)bq;
        const float4 e4v = *(const float4*)&En[4 * q];
        const float en[4] = {e4v.x, e4v.y, e4v.z, e4v.w};
        const int fl[4] = {(int)(__float_as_uint(e4v.x) & 3u),
                           (int)(__float_as_uint(e4v.y) & 3u),
                           (int)(__float_as_uint(e4v.z) & 3u),
                           (int)(__float_as_uint(e4v.w) & 3u)};
        const float s01 = en[0] + en[1], p01 = en[0] * en[1];
        const float s23 = en[2] + en[3], p23 = en[2] * en[3];
        const float e1 = s01 + s23;
        const float e2 = fmaf(s01, s23, p01 + p23);
        const float e3 = fmaf(s01, p23, s23 * p01);
        const float e4 = p01 * p23;
        float nA3 = 0.f, nA2 = 0.f, nA1 = 0.f, nA0 = 0.f;
        float nP3 = 0.f, nP2 = 0.f, nP1 = 0.f, nP0 = 0.f;
#pragma unroll
        for (int j = 0; j < 4; ++j) {
            const float b1 = e1 - en[j];
            const float b2 = fmaf(-en[j], b1, e2);
            const float b3 = fmaf(-en[j], b2, e3);
            const float nn = (float)(fl[j] >> 1) * en[j];
            const float pp = (float)(fl[j] & 1) * en[j];
            nA3 += nn; nA2 = fmaf(nn, b1, nA2); nA1 = fmaf(nn, b2, nA1); nA0 = fmaf(nn, b3, nA0);
            nP3 += pp; nP2 = fmaf(pp, b1, nP2); nP1 = fmaf(pp, b2, nP1); nP0 = fmaf(pp, b3, nP0);
        }
        const int pq = q + (q >> 4);   // bank-skewed physical index
        CeAll[pq] = make_float4(e1, e2, e3, e4);
        __half2 hA0 = __floats2half2_rn(nA3, nA2);
        __half2 hA1 = __floats2half2_rn(nA1, nA0);
        __half2 hP0 = __floats2half2_rn(nP3, nP2);
        __half2 hP1 = __floats2half2_rn(nP1, nP0);
        ChAll[pq] = make_uint4(reinterpret_cast<unsigned&>(hA0), reinterpret_cast<unsigned&>(hA1),
                               reinterpret_cast<unsigned&>(hP0), reinterpret_cast<unsigned&>(hP1));
    }
    // ---- Phase 3b: per-bucket tail sums, 4 threads/bucket + shfl reduce ----
    if (tid < NB * 4) {
        const int k = tid >> 2, o = tid & 3;
        float g1a=0,g2a=0,g3a=0,h1a=0,h2a=0,h3a=0,s0a=0;
        float g1p=0,g2p=0,g3p=0,h1p=0,h2p=0,h3p=0,s0p=0;
        for (int s = segStart[k] + o; s < segStart[k + 1]; s += 4) {
            const float en = En[s];
            const int f = (int)(__float_as_uint(en) & 3u);
            if (!f) continue;
            const float en2 = en * en, en3 = en2 * en;
            const float ren = __builtin_amdgcn_rcpf(en);
            const float ren2 = ren * ren, ren3 = ren2 * ren;
            const float nf = (float)(f >> 1), pf = (float)(f & 1);
            g1a = fmaf(nf,en,g1a);  g2a = fmaf(nf,en2,g2a);  g3a = fmaf(nf,en3,g3a);
            h1a = fmaf(nf,ren,h1a); h2a = fmaf(nf,ren2,h2a); h3a = fmaf(nf,ren3,h3a); s0a += nf;
            g1p = fmaf(pf,en,g1p);  g2p = fmaf(pf,en2,g2p);  g3p = fmaf(pf,en3,g3p);
            h1p = fmaf(pf,ren,h1p); h2p = fmaf(pf,ren2,h2p); h3p = fmaf(pf,ren3,h3p); s0p += pf;
        }
#define RED4(v) v += __shfl_xor(v, 2); v += __shfl_xor(v, 1)
        RED4(g1a); RED4(g2a); RED4(g3a); RED4(h1a); RED4(h2a); RED4(h3a); RED4(s0a);
        RED4(g1p); RED4(g2p); RED4(g3p); RED4(h1p); RED4(h2p); RED4(h3p); RED4(s0p);
#undef RED4
        if (o == 0) {
            TabF[(0*7+0)*TCOLS+k+2]=g1a; TabF[(0*7+1)*TCOLS+k+2]=g2a; TabF[(0*7+2)*TCOLS+k+2]=g3a;
            TabF[(0*7+3)*TCOLS+k+2]=h1a; TabF[(0*7+4)*TCOLS+k+2]=h2a; TabF[(0*7+5)*TCOLS+k+2]=h3a;
            TabF[(0*7+6)*TCOLS+k+2]=s0a;
            TabF[(1*7+0)*TCOLS+k+2]=g1p; TabF[(1*7+1)*TCOLS+k+2]=g2p; TabF[(1*7+2)*TCOLS+k+2]=g3p;
            TabF[(1*7+3)*TCOLS+k+2]=h1p; TabF[(1*7+4)*TCOLS+k+2]=h2p; TabF[(1*7+5)*TCOLS+k+2]=h3p;
            TabF[(1*7+6)*TCOLS+k+2]=s0p;
        }
    }
    __syncthreads();
    // ---- Phase 3c: wave-parallel weighted scans (14 rows over 4 waves) ----
    for (int rowi = wvid; rowi < 14; rowi += 4) {
        const int r7 = rowi % 7;
        float* Trow = &TabF[rowi * TCOLS];
        float v = (lane < NB) ? Trow[lane + 2] : 0.f;
        if (r7 < 3) {          // prefix: y[k] = x[k] + kp*y[k-1]
            float kp = (r7 == 0) ? kap1 : (r7 == 1 ? kap2 : kap3);
#pragma unroll
            for (int d = 1; d < 64; d <<= 1) {
                const float o = __shfl_up(v, d);
                if (lane >= d) v = fmaf(kp, o, v);
                kp *= kp;
            }
        } else {               // suffix: y[k] = x[k] + kp*y[k+1]  (kp=1: plain sum)
            float kp = (r7 == 3) ? kap1 : (r7 == 4 ? kap2 : (r7 == 5 ? kap3 : 1.0f));
#pragma unroll
            for (int d = 1; d < 64; d <<= 1) {
                float o = __shfl_down(v, d);
                if (lane + d > 63) o = 0.f;
                v = fmaf(kp, o, v);
                kp *= kp;
            }
        }
        if (lane < NB) Trow[lane + 2] = v;
    }
    __syncthreads();

    // ---- Phase 4: main — contiguous quad ownership (within-wave homogeneous) ----
    float AN[4] = {0,0,0,0}, AP[4] = {0,0,0,0};
    const int q0 = tid;
    if (q0 < nQ) {
        const float4 x4 = *(const float4*)&En[4 * q0];
        const float xb[4] = {x4.x, x4.y, x4.z, x4.w};
        const int ib = BktQ[q0];
        const int klo = ib > 0 ? ib - 1 : 0;
        const int khi = ib < NB - 1 ? ib + 1 : NB - 1;
        const int qs  = segStart[klo] >> 2;
        const int qe  = segStart[khi + 1] >> 2;
        const int qo0 = segStart[ib] >> 2;
        const int qo1 = segStart[ib + 1] >> 2;

        auto quadrun = [&](int a0, int a1, const float* xs) {
            for (int q = a0; q < a1; ++q) {
                const int pq = q + (q >> 4);
                const float4 ce = CeAll[pq];
                const uint4 ch = ChAll[pq];
                const float2 a01 = __half22float2(*(const __half2*)&ch.x);
                const float2 a23 = __half22float2(*(const __half2*)&ch.y);
                const float2 p01 = __half22float2(*(const __half2*)&ch.z);
                const float2 p23 = __half22float2(*(const __half2*)&ch.w);
#pragma unroll
                for (int i = 0; i < 4; ++i) {
                    const float x = xs[i];
                    float t = x + ce.x; t = fmaf(t, x, ce.y); t = fmaf(t, x, ce.z);
                    const float D = fmaf(t, x, ce.w);
                    float u = fmaf(a01.x, x, a01.y); u = fmaf(u, x, a23.x);
                    const float NA = fmaf(u, x, a23.y);
                    float v = fmaf(p01.x, x, p01.y); v = fmaf(v, x, p23.x);
                    const float NP = fmaf(v, x, p23.y);
                    const float rd = __builtin_amdgcn_rcpf(D);
                    AN[i] = fmaf(NA, rd, AN[i]);
                    AP[i] = fmaf(NP, rd, AP[i]);
                }
            }
        };
        float xsl[4], xsh[4];
#pragma unroll
        for (int i = 0; i < 4; ++i) { xsl[i] = xb[i] * eWm; xsh[i] = xb[i] * kap1; }
        quadrun(qs,  qo0, xsl);   // below-band buckets: fc = e^W
        quadrun(qo0, qo1, xb);    // own bucket: fc = 1
        quadrun(qo1, qe,  xsh);   // above-band buckets: fc = kappa

        // 3-term out-of-band tails
        const float P1a = TabF[(0*7+0)*TCOLS+ib],   P2a = TabF[(0*7+1)*TCOLS+ib],   P3a = TabF[(0*7+2)*TCOLS+ib];
        const float S1a = TabF[(0*7+3)*TCOLS+ib+4], S2a = TabF[(0*7+4)*TCOLS+ib+4], S3a = TabF[(0*7+5)*TCOLS+ib+4];
        const float S0a = TabF[(0*7+6)*TCOLS+ib+4];
        const float P1p = TabF[(1*7+0)*TCOLS+ib],   P2p = TabF[(1*7+1)*TCOLS+ib],   P3p = TabF[(1*7+2)*TCOLS+ib];
        const float S1p = TabF[(1*7+3)*TCOLS+ib+4], S2p = TabF[(1*7+4)*TCOLS+ib+4], S3p = TabF[(1*7+5)*TCOLS+ib+4];
        const float S0p = TabF[(1*7+6)*TCOLS+ib+4];
#pragma unroll
        for (int i = 0; i < 4; ++i) {
            const float eb = xb[i];
            const float rb = __builtin_amdgcn_rcpf(eb);
            const float tq = rb * kap2, sq = eb * kap2;
            const float tq2 = tq * tq, tq3 = tq2 * tq;
            const float sq2 = sq * sq, sq3 = sq2 * sq;
            AN[i] += tq * P1a - tq2 * P2a + tq3 * P3a
                   + S0a - sq * S1a + sq2 * S2a - sq3 * S3a;
            AP[i] += tq * P1p - tq2 * P2p + tq3 * P3p
                   + S0p - sq * S1p + sq2 * S2p - sq3 * S3p;
        }
    }
    __syncthreads();   // all Cq reads done -> overlay RankA/RankP

    // ---- Phase 5: write ranks BY SLOT ----
    if (q0 < nQ) {
#pragma unroll
        for (int i = 0; i < 4; ++i) {
            RankA[4 * q0 + i] = AN[i];
            RankP[4 * q0 + i] = AP[i];
        }
    }
    __syncthreads();

    // ---- Phase 6: gather via register slot[], write rank_m ----
#pragma unroll
    for (int i = 0; i < 4; ++i) {
        const int c = tid + i * NT;
        const bool pf = (cat[i] & 1) != 0;
        const bool nf = (cat[i] & 2) != 0;
        const float rk_ = (pf ? 1.f + RankA[slot[i]] : 0.f) +
                          (nf ? 1.f + RankP[slot[i]] : 0.f);
        rank_ws[m * (B * B) + r * B + c] = rk_;
    }
}

__global__ __launch_bounds__(NT, 8)
void combine_kernel(const float* __restrict__ rank_ws,
                    const float* __restrict__ w_v, const float* __restrict__ w_l,
                    float* __restrict__ out) {
    const int i4 = (blockIdx.x * NT + threadIdx.x) * 4;
    const float4 rv = *(const float4*)&rank_ws[i4];
    const float4 rl = *(const float4*)&rank_ws[B * B + i4];
    const float4 wv = *(const float4*)&w_v[i4];
    const float4 wl = *(const float4*)&w_l[i4];
    float4 o;
    o.x = 61.f * (wv.x / (60.f + rv.x) + wl.x / (60.f + rl.x));
    o.y = 61.f * (wv.y / (60.f + rv.y) + wl.y / (60.f + rl.y));
    o.z = 61.f * (wv.z / (60.f + rv.z) + wl.z / (60.f + rl.z));
    o.w = 61.f * (wv.w / (60.f + rv.w) + wl.w / (60.f + rl.w));
    *(float4*)&out[i4] = o;
}

extern "C" void kernel_launch(void* const* d_in, const int* in_sizes, int n_in,
                              void* d_out, int out_size, void* d_ws, size_t ws_size,
                              hipStream_t stream) {
    const float* s_v = (const float*)d_in[0];
    const float* s_l = (const float*)d_in[1];
    const int* pos_mask = (const int*)d_in[2];
    const int* neg_mask = (const int*)d_in[3];
    const float* w_v = (const float*)d_in[4];
    const float* w_l = (const float*)d_in[5];
    float* out = (float*)d_out;
    float* rank_ws = (float*)d_ws;   // 2 * 1024 * 1024 floats = 8 MB

    rank_one_kernel<<<2 * B, NT, 0, stream>>>(s_v, s_l, pos_mask, neg_mask, rank_ws);
    combine_kernel<<<(B * B) / (NT * 4), NT, 0, stream>>>(rank_ws, w_v, w_l, out);
}